// Round 13
// baseline (699.066 us; speedup 1.0000x reference)
//
#include <hip/hip_runtime.h>

#define H 512
#define TSTEPS 196
#define FLEN 784
#define NBATCH 256

typedef float f4 __attribute__((ext_vector_type(4)));
typedef unsigned long long ull;

// ws byte layout:
//   [0MB) Wh1^T  [1MB) Wi2^T   <- L1-list pair (partner = +1MB)
//   [2MB) Wh2^T  [3MB) Wi3^T   <- L2-list pair (partner = +1MB)
//   [4MB) 2KB zero column (zeroA)   [5MB) 2KB zero column (zeroB)
//   [float 1311232) mask bitmaps mb1,mb2,mb3 (each 196*8 ull)
// Dead-lane redirect offsets (pair-relative, same for both pair members):
//   pair1: bA=0MB -> +4MB = zeroA, bB=1MB -> +4MB = 5MB = zeroB
//   pair2: bA=2MB -> +2MB = zeroA, bB=3MB -> +2MB = zeroB
#define PAD1 4194304u
#define PAD2 2097152u
#define ZCOL1_F 1048576
#define ZCOL2_F 1310720
#define MBOFF_F 1311232

__global__ void transpose4(const float* __restrict__ a,
                           const float* __restrict__ b,
                           const float* __restrict__ c,
                           const float* __restrict__ d,
                           float* __restrict__ ws)
{
    __shared__ float tile[32][33];
    const float* src = (blockIdx.z == 0) ? a : (blockIdx.z == 1) ? b
                     : (blockIdx.z == 2) ? c : d;
    float* dst = ws + (size_t)blockIdx.z * (H * H);
    int bx = blockIdx.x * 32, by = blockIdx.y * 32;
    int tx = threadIdx.x, ty = threadIdx.y;
    for (int r = ty; r < 32; r += 8)
        tile[r][tx] = src[(by + r) * H + bx + tx];
    __syncthreads();
    for (int r = ty; r < 32; r += 8)
        dst[(bx + r) * H + by + tx] = tile[tx][r];
}

// z<3: pack masks into bitmaps (mb[z][t*8+w] bit l = mask[64w+l, t] != 0)
// z==3: zero the two 2KB pad columns
__global__ void maskbits(const float* __restrict__ m1, const float* __restrict__ m2,
                         const float* __restrict__ m3, float* __restrict__ ws)
{
    int t = blockIdx.x;          // 0..195
    int z = blockIdx.y;          // 0..3
    int l = threadIdx.x;         // 0..63
    if (z == 3) {
        int idx = t * 64 + l;
        if (idx < 512)            ws[ZCOL1_F + idx] = 0.0f;
        else if (idx < 1024)      ws[ZCOL2_F + idx - 512] = 0.0f;
        return;
    }
    ull* mb = (ull*)(ws + MBOFF_F);
    const float* src = (z == 0) ? m1 : (z == 1) ? m2 : m3;
    for (int w = 0; w < 8; ++w) {
        ull bl = __ballot(src[(w * 64 + l) * FLEN + t] != 0.0f);
        if (l == 0) mb[(size_t)z * (TSTEPS * 8) + t * 8 + w] = bl;
    }
}

// Pair gather over list[lo,hi) (entries = byte column offsets, k<<11).
// Both loads share the voffset; DEAD LANES (consumer-mask nibble == 0) are
// redirected to the L1-hot zero column (zoff) -> +0.0f, bit-exact, and the
// lane stops pulling cold lines through L1. 4-unrolled, 8 loads in flight.
__device__ __forceinline__ void gpair(const char* __restrict__ bA,
                                      const char* __restrict__ bB,
                                      const int* __restrict__ list,
                                      int lo, int hi, unsigned uoff, unsigned zoff,
                                      bool pA, bool pB, f4& accA, f4& accB)
{
    int i = lo;
    for (; i + 4 <= hi; i += 4) {
        unsigned t0 = (unsigned)list[i]     + uoff;
        unsigned t1 = (unsigned)list[i + 1] + uoff;
        unsigned t2 = (unsigned)list[i + 2] + uoff;
        unsigned t3 = (unsigned)list[i + 3] + uoff;
        unsigned a0 = pA ? t0 : zoff, b0 = pB ? t0 : zoff;
        unsigned a1 = pA ? t1 : zoff, b1 = pB ? t1 : zoff;
        unsigned a2 = pA ? t2 : zoff, b2 = pB ? t2 : zoff;
        unsigned a3 = pA ? t3 : zoff, b3 = pB ? t3 : zoff;
        f4 va0 = *(const f4*)(bA + a0), vb0 = *(const f4*)(bB + b0);
        f4 va1 = *(const f4*)(bA + a1), vb1 = *(const f4*)(bB + b1);
        f4 va2 = *(const f4*)(bA + a2), vb2 = *(const f4*)(bB + b2);
        f4 va3 = *(const f4*)(bA + a3), vb3 = *(const f4*)(bB + b3);
        accA += (va0 + va1) + (va2 + va3);
        accB += (vb0 + vb1) + (vb2 + vb3);
    }
    for (; i < hi; ++i) {
        unsigned t0 = (unsigned)list[i] + uoff;
        unsigned a0 = pA ? t0 : zoff, b0 = pB ? t0 : zoff;
        accA += *(const f4*)(bA + a0);
        accB += *(const f4*)(bB + b0);
    }
}

__device__ __forceinline__ float sum8(const float* __restrict__ p, int j)
{
    float s0 = p[j] + p[512 + j];
    float s1 = p[1024 + j] + p[1536 + j];
    float s2 = p[2048 + j] + p[2560 + j];
    float s3 = p[3072 + j] + p[3584 + j];
    return (s0 + s1) + (s2 + s3);
}

__device__ __forceinline__ float mbit(const ull* __restrict__ mb, int t, int j)
{
    return ((mb[t * 8 + (j >> 6)] >> (j & 63)) & 1ull) ? 1.0f : 0.0f;
}

// lag pipeline, per iteration t = 0..TSTEPS+1:
//   P0: ONE merged gather phase @ lists from t-1; per-thread dead-lane
//       redirect by consumer-mask nibble:
//       pU1 = Wh1@L1 [nib1=mb1(t)]; pU2 = Wi2@L1 + Wh2@L2 [nib2=mb2(t-1)];
//       pU3 = Wi3@L2 [nib3=mb3(t-2)]                                  | B1
//   P1: lower half U1(t); upper half U2(t-1), U3(t-2); ballots        | B2
//   P2: build lists from ballots                                      | B3
__global__ __launch_bounds__(1024)
void lsnn_main(const float* __restrict__ x,
               const float* __restrict__ Wi1,
               const float* __restrict__ bi1, const float* __restrict__ bh1,
               const float* __restrict__ bi2, const float* __restrict__ bh2,
               const float* __restrict__ bi3,
               const float* __restrict__ Wo,  const float* __restrict__ bo,
               const float* __restrict__ tau1, const float* __restrict__ tau2,
               const float* __restrict__ tau3,
               const float* __restrict__ ws,
               float* __restrict__ out)
{
    const char* wsb  = (const char*)ws;
    const char* B_H1 = wsb;
    const char* B_I2 = wsb + (1u << 20);
    const char* B_H2 = wsb + (2u << 20);
    const char* B_I3 = wsb + (3u << 20);
    const ull* mb1 = (const ull*)(ws + MBOFF_F);
    const ull* mb2 = mb1 + TSTEPS * 8;
    const ull* mb3 = mb2 + TSTEPS * 8;

    const int n    = blockIdx.x;
    const int tid  = threadIdx.x;
    const int lane = tid & 63;
    const bool lowh = tid < 512;
    const int j    = lowh ? tid : tid - 512;   // neuron index within half
    const int w8   = (tid >> 6) & 7;           // wave id within half
    const int u    = tid & 127;                // 16B slice id (rows 4u..4u+3)
    const int g    = tid >> 7;                 // gather group 0..7
    const unsigned uoff = (unsigned)u << 4;
    const unsigned z1 = PAD1 + uoff;           // pair-1 redirect offset
    const unsigned z2 = PAD2 + uoff;           // pair-2 redirect offset

    __shared__ f4 pU1[8][128], pU2[8][128], pU3[8][128];
    __shared__ int L1[H], L2[H];
    __shared__ ull ballS[16];    // [0..7]=ball(s1), [8..15]=ball(s2)

    // per-half parameter/state registers
    float4 wi; float bs1, ro1, omr1, mem1, b1, s1;           // lower
    float bs2, ro2, omr2, mem2, b2, s2;                      // upper
    float bs3, ro3, omr3, mem3, b3, s3, cnt3;                // upper
    const float alpha = expf(-1.0f / 20.0f);
    const float oma = 1.0f - alpha;
    if (lowh) {
        wi  = reinterpret_cast<const float4*>(Wi1)[j];
        bs1 = bi1[j] + bh1[j];
        ro1 = expf(-1.0f / tau1[j]); omr1 = 1.0f - ro1;
        mem1 = 0.f; b1 = 0.01f; s1 = 0.f;
    } else {
        bs2 = bi2[j] + bh2[j];
        bs3 = bi3[j];
        ro2 = expf(-1.0f / tau2[j]); omr2 = 1.0f - ro2;
        ro3 = expf(-1.0f / tau3[j]); omr3 = 1.0f - ro3;
        mem2 = 0.f; b2 = 0.01f; s2 = 0.f;
        mem3 = 0.f; b3 = 0.01f; s3 = 0.f; cnt3 = 0.f;
    }

    int na1 = 0, na2 = 0;
    const float* xr = x + n * FLEN;

    if (tid < 16) ballS[tid] = 0ull;
    __syncthreads();

    for (int t = 0; t <= TSTEPS + 1; ++t) {
        // ---------------- P0: merged gather with dead-lane redirect --------
        {
            // consumer-mask nibbles for this thread's rows 4u..4u+3
            unsigned nib1 = 0, nib2 = 0, nib3 = 0;
            if (t < TSTEPS)
                nib1 = (unsigned)((mb1[t * 8 + (u >> 4)] >> ((u & 15) * 4)) & 0xFull);
            if (t >= 1 && t - 1 < TSTEPS)
                nib2 = (unsigned)((mb2[(t - 1) * 8 + (u >> 4)] >> ((u & 15) * 4)) & 0xFull);
            if (t >= 2)
                nib3 = (unsigned)((mb3[(t - 2) * 8 + (u >> 4)] >> ((u & 15) * 4)) & 0xFull);
            bool p1 = nib1 != 0, p2 = nib2 != 0, p3 = nib3 != 0;

            int tot = na1 + na2;
            int lo = (tot * g) >> 3, hi = (tot * (g + 1)) >> 3;
            f4 aU1 = (f4)0.0f, aU2 = (f4)0.0f, aU3 = (f4)0.0f;
            int mi = lo < na1 ? (hi < na1 ? hi : na1) : na1;
            if (lo < mi)
                gpair(B_H1, B_I2, L1, lo, mi, uoff, z1, p1, p2, aU1, aU2);
            int lo2 = (lo > na1 ? lo : na1) - na1, hi2 = hi - na1;
            if (lo2 < hi2)
                gpair(B_H2, B_I3, L2, lo2, hi2, uoff, z2, p2, p3, aU2, aU3);
            pU1[g][u] = aU1;
            pU2[g][u] = aU2;
            pU3[g][u] = aU3;
        }
        __syncthreads();                           // B1

        // ---------------- P1: updates (both halves busy) ----------------
        if (lowh) {
            ull ball = 0;
            if (t < TSTEPS) {
                float mk1 = mbit(mb1, t, j);
                int base = (t < 48) ? (4 * t) : (FLEN - 4);
                float4 xv = *reinterpret_cast<const float4*>(xr + base);
                float h1 = wi.x * xv.x + wi.y * xv.y + wi.z * xv.z + wi.w * xv.w
                         + bs1 + sum8((const float*)&pU1[0][0], j);
                b1 = ro1 * b1 + omr1 * s1;
                float Bth = 0.01f + 1.8f * b1;
                float nm = mem1 * alpha + oma * h1 - Bth * s1;
                mem1 = (mk1 == 0.0f) ? mem1 : nm;
                s1 = (mem1 - Bth > 0.0f) ? mk1 : 0.0f;
                ball = __ballot(s1 != 0.0f);
            }
            if (lane == 0) ballS[w8] = ball;
        } else {
            ull ball = 0;
            int t2 = t - 1;
            if (t2 >= 0 && t2 < TSTEPS) {
                float mk2 = mbit(mb2, t2, j);
                float h2 = bs2 + sum8((const float*)&pU2[0][0], j);
                b2 = ro2 * b2 + omr2 * s2;
                float Bth = 0.01f + 1.8f * b2;
                float nm = mem2 * alpha + oma * h2 - Bth * s2;
                mem2 = (mk2 == 0.0f) ? mem2 : nm;
                s2 = (mem2 - Bth > 0.0f) ? mk2 : 0.0f;
                ball = __ballot(s2 != 0.0f);
            }
            if (lane == 0) ballS[8 + w8] = ball;
            int t3 = t - 2;
            if (t3 >= 0 && t3 < TSTEPS) {
                float mk3 = mbit(mb3, t3, j);
                float h3 = bs3 + sum8((const float*)&pU3[0][0], j);
                b3 = ro3 * b3 + omr3 * s3;
                float Bth = 0.01f + 1.8f * b3;
                float nm = mem3 * alpha + oma * h3 - Bth * s3;
                mem3 = (mk3 == 0.0f) ? mem3 : nm;
                s3 = (mem3 - Bth > 0.0f) ? mk3 : 0.0f;
                cnt3 += s3;                        // deferred output GEMV
            }
        }
        __syncthreads();                           // B2

        // ---------------- P2: build lists from ballots ----------------
        {
            ull bw[16];
            int c[16];
#pragma unroll
            for (int w = 0; w < 16; ++w) { bw[w] = ballS[w]; c[w] = __popcll(bw[w]); }
            int t1 = 0, t2s = 0;
#pragma unroll
            for (int w = 0; w < 8; ++w) { t1 += c[w]; t2s += c[8 + w]; }
            if (lowh) {
                int pos = 0;
#pragma unroll
                for (int w = 0; w < 8; ++w) if (w < w8) pos += c[w];
                pos += __popcll(bw[w8] & ((1ull << lane) - 1ull));
                if ((bw[w8] >> lane) & 1ull) L1[pos] = j << 11;
            } else {
                int pos = 0;
#pragma unroll
                for (int w = 0; w < 8; ++w) if (w < w8) pos += c[8 + w];
                pos += __popcll(bw[8 + w8] & ((1ull << lane) - 1ull));
                if ((bw[8 + w8] >> lane) & 1ull) L2[pos] = j << 11;
            }
            na1 = t1; na2 = t2s;
        }
        __syncthreads();                           // B3
    }

    // ---- output: out[n,o] = (Wo[o,:]·cnt3 + T*bo[o]) / T ----
    float* c3 = (float*)&pU1[0][0];
    if (!lowh) c3[j] = cnt3;
    __syncthreads();
    int wv = tid >> 6;   // 0..15
    for (int o = wv; o < 10; o += 16) {
        float p = 0.0f;
        for (int i = lane; i < H; i += 64)
            p += Wo[o * H + i] * c3[i];
        for (int off = 32; off > 0; off >>= 1)
            p += __shfl_down(p, off);
        if (lane == 0)
            out[n * 10 + o] = (p + 196.0f * bo[o]) / 196.0f;
    }
}

extern "C" void kernel_launch(void* const* d_in, const int* in_sizes, int n_in,
                              void* d_out, int out_size, void* d_ws, size_t ws_size,
                              hipStream_t stream)
{
    const float* x    = (const float*)d_in[0];
    const float* Wi1  = (const float*)d_in[1];
    const float* bi1  = (const float*)d_in[2];
    const float* Wh1  = (const float*)d_in[3];
    const float* bh1  = (const float*)d_in[4];
    const float* Wi2  = (const float*)d_in[5];
    const float* bi2  = (const float*)d_in[6];
    const float* Wh2  = (const float*)d_in[7];
    const float* bh2  = (const float*)d_in[8];
    const float* Wi3  = (const float*)d_in[9];
    const float* bi3  = (const float*)d_in[10];
    const float* Wo   = (const float*)d_in[11];
    const float* bo   = (const float*)d_in[12];
    const float* tau1 = (const float*)d_in[13];
    const float* tau2 = (const float*)d_in[14];
    const float* tau3 = (const float*)d_in[15];
    const float* m1   = (const float*)d_in[16];
    const float* m2   = (const float*)d_in[17];
    const float* m3   = (const float*)d_in[18];

    float* ws  = (float*)d_ws;
    float* out = (float*)d_out;

    // pre-pass: transpose Wh1,Wi2,Wh2,Wi3 into 1MB slots; bitmaps + zero cols
    transpose4<<<dim3(16, 16, 4), dim3(32, 8, 1), 0, stream>>>(Wh1, Wi2, Wh2, Wi3, ws);
    maskbits<<<dim3(TSTEPS, 4, 1), 64, 0, stream>>>(m1, m2, m3, ws);

    // main persistent kernel: 1 sample per workgroup (256 WGs, 1024 thr, 16 waves)
    lsnn_main<<<NBATCH, 1024, 0, stream>>>(x, Wi1, bi1, bh1, bi2, bh2, bi3,
                                           Wo, bo, tau1, tau2, tau3, ws, out);
}

// Round 14
// 629.125 us; speedup vs baseline: 1.1112x; 1.1112x over previous
//
#include <hip/hip_runtime.h>

#define H 512
#define TSTEPS 196
#define FLEN 784
#define NBATCH 256

typedef float f4 __attribute__((ext_vector_type(4)));
typedef unsigned long long ull;

// ws byte layout:
//   [0MB) Wh1^T  [1MB) Wi2^T   <- L1-list pair (partner = +1MB)
//   [2MB) Wh2^T  [3MB) Wi3^T   <- L2-list pair (partner = +1MB)
//   [4MB) mask bitmaps mb1, mb2, mb3 (each 196*8 ull)
#define MBOFF_F 1048576   // float offset of bitmaps (= 4MB bytes)

__global__ void transpose4(const float* __restrict__ a,
                           const float* __restrict__ b,
                           const float* __restrict__ c,
                           const float* __restrict__ d,
                           float* __restrict__ ws)
{
    __shared__ float tile[32][33];
    const float* src = (blockIdx.z == 0) ? a : (blockIdx.z == 1) ? b
                     : (blockIdx.z == 2) ? c : d;
    float* dst = ws + (size_t)blockIdx.z * (H * H);
    int bx = blockIdx.x * 32, by = blockIdx.y * 32;
    int tx = threadIdx.x, ty = threadIdx.y;
    for (int r = ty; r < 32; r += 8)
        tile[r][tx] = src[(by + r) * H + bx + tx];
    __syncthreads();
    for (int r = ty; r < 32; r += 8)
        dst[(bx + r) * H + by + tx] = tile[tx][r];
}

// pack binary masks into bitmaps: mb[z][t*8+w] bit l = (mask[z][64w+l, t] != 0)
__global__ void maskbits(const float* __restrict__ m1, const float* __restrict__ m2,
                         const float* __restrict__ m3, ull* __restrict__ mb)
{
    int t = blockIdx.x;          // 0..195
    int z = blockIdx.y;          // 0..2
    int l = threadIdx.x;         // 0..63
    const float* src = (z == 0) ? m1 : (z == 1) ? m2 : m3;
    for (int w = 0; w < 8; ++w) {
        ull bl = __ballot(src[(w * 64 + l) * FLEN + t] != 0.0f);
        if (l == 0) mb[(size_t)z * (TSTEPS * 8) + t * 8 + w] = bl;
    }
}

// Pair gather over list segment [lo,hi): for each entry (byte column offset),
// load this thread's 16B slice from TWO matrices (bB = bA + 1MB shares the
// voffset) into separate accumulators. 4-unrolled -> 8 loads in flight.
__device__ __forceinline__ void gpair(const char* __restrict__ bA,
                                      const char* __restrict__ bB,
                                      const unsigned* __restrict__ list,
                                      int lo, int hi, unsigned uoff,
                                      f4& accA, f4& accB)
{
    int i = lo;
    for (; i + 4 <= hi; i += 4) {
        unsigned o0 = list[i]     + uoff;
        unsigned o1 = list[i + 1] + uoff;
        unsigned o2 = list[i + 2] + uoff;
        unsigned o3 = list[i + 3] + uoff;
        f4 va0 = *(const f4*)(bA + o0), vb0 = *(const f4*)(bB + o0);
        f4 va1 = *(const f4*)(bA + o1), vb1 = *(const f4*)(bB + o1);
        f4 va2 = *(const f4*)(bA + o2), vb2 = *(const f4*)(bB + o2);
        f4 va3 = *(const f4*)(bA + o3), vb3 = *(const f4*)(bB + o3);
        accA += (va0 + va1) + (va2 + va3);
        accB += (vb0 + vb1) + (vb2 + vb3);
    }
    for (; i < hi; ++i) {
        unsigned o = list[i] + uoff;
        accA += *(const f4*)(bA + o);
        accB += *(const f4*)(bB + o);
    }
}

__device__ __forceinline__ float sum8(const float* __restrict__ p, int j)
{
    float s0 = p[j] + p[512 + j];
    float s1 = p[1024 + j] + p[1536 + j];
    float s2 = p[2048 + j] + p[2560 + j];
    float s3 = p[3072 + j] + p[3584 + j];
    return (s0 + s1) + (s2 + s3);
}

__device__ __forceinline__ float mbit(const ull* __restrict__ mb, int t, int j)
{
    return ((mb[t * 8 + (j >> 6)] >> (j & 63)) & 1ull) ? 1.0f : 0.0f;
}

// schedule (lag pipeline): per iteration t = 0..TSTEPS+1
//   P0: ONE gather phase @ lists built in t-1:
//       pU1 = Wh1@L1(s1(t-1));  pU2 = Wi2@L1 + Wh2@L2(s2(t-2));  pU3 = Wi3@L2
//   P1: lower half: U1(t);  upper half: U2(t-1), U3(t-2); ballots -> lists
__global__ __launch_bounds__(1024)
void lsnn_main(const float* __restrict__ x,
               const float* __restrict__ Wi1,
               const float* __restrict__ bi1, const float* __restrict__ bh1,
               const float* __restrict__ bi2, const float* __restrict__ bh2,
               const float* __restrict__ bi3,
               const float* __restrict__ Wo,  const float* __restrict__ bo,
               const float* __restrict__ tau1, const float* __restrict__ tau2,
               const float* __restrict__ tau3,
               const float* __restrict__ ws,
               float* __restrict__ out)
{
    const char* wsb = (const char*)ws;
    const char* B_H1 = wsb;
    const char* B_H2 = wsb + (2u << 20);
    const ull* mb1 = (const ull*)(ws + MBOFF_F);
    const ull* mb2 = mb1 + TSTEPS * 8;
    const ull* mb3 = mb2 + TSTEPS * 8;

    const int n    = blockIdx.x;
    const int tid  = threadIdx.x;
    const int lane = tid & 63;
    const bool lowh = tid < 512;
    const int j    = lowh ? tid : tid - 512;   // neuron index within the half
    const int w8   = (tid >> 6) & 7;           // wave id within the half
    const int u    = tid & 127;                // 16B slice id
    const int g    = tid >> 7;                 // gather group 0..7
    const unsigned uoff = (unsigned)u << 4;

    __shared__ f4       pU1[8][128], pU2[8][128], pU3[8][128];
    __shared__ unsigned L1[H], L2[H];
    __shared__ ull      ballS[16];   // [0..7]=ball(s1), [8..15]=ball(s2)

    // per-half parameter/state registers
    float4 wi; float bs1, ro1, omr1, mem1, b1, s1;           // lower
    float bs2, ro2, omr2, mem2, b2, s2;                      // upper
    float bs3, ro3, omr3, mem3, b3, s3, cnt3;                // upper
    const float alpha = expf(-1.0f / 20.0f);
    const float oma = 1.0f - alpha;
    if (lowh) {
        wi  = reinterpret_cast<const float4*>(Wi1)[j];
        bs1 = bi1[j] + bh1[j];
        ro1 = expf(-1.0f / tau1[j]); omr1 = 1.0f - ro1;
        mem1 = 0.f; b1 = 0.01f; s1 = 0.f;
    } else {
        bs2 = bi2[j] + bh2[j];
        bs3 = bi3[j];
        ro2 = expf(-1.0f / tau2[j]); omr2 = 1.0f - ro2;
        ro3 = expf(-1.0f / tau3[j]); omr3 = 1.0f - ro3;
        mem2 = 0.f; b2 = 0.01f; s2 = 0.f;
        mem3 = 0.f; b3 = 0.01f; s3 = 0.f; cnt3 = 0.f;
    }

    int na1 = 0, na2 = 0;
    const float* xr = x + n * FLEN;

    if (tid < 16) ballS[tid] = 0ull;
    __syncthreads();

    for (int t = 0; t <= TSTEPS + 1; ++t) {
        // ---------------- P0: single merged gather phase ----------------
        {
            int tot = na1 + na2;
            int lo = (tot * g) >> 3, hi = (tot * (g + 1)) >> 3;
            f4 aU1 = (f4)0.0f, aU2 = (f4)0.0f, aU3 = (f4)0.0f;
            int mi = lo < na1 ? (hi < na1 ? hi : na1) : na1;   // end of L1 part
            if (lo < mi)
                gpair(B_H1, B_H1 + (1u << 20), L1, lo, mi, uoff, aU1, aU2);
            int lo2 = (lo > na1 ? lo : na1) - na1, hi2 = hi - na1;
            if (lo2 < hi2)
                gpair(B_H2, B_H2 + (1u << 20), L2, lo2, hi2, uoff, aU2, aU3);
            pU1[g][u] = aU1;
            pU2[g][u] = aU2;
            pU3[g][u] = aU3;
        }
        __syncthreads();                           // B1 (expensive: load drain)

        // ---------------- P1: updates (both halves busy) ----------------
        if (lowh) {
            ull ball = 0;
            if (t < TSTEPS) {
                float mk1 = mbit(mb1, t, j);
                int base = (t < 48) ? (4 * t) : (FLEN - 4);
                float4 xv = *reinterpret_cast<const float4*>(xr + base);
                float h1 = wi.x * xv.x + wi.y * xv.y + wi.z * xv.z + wi.w * xv.w
                         + bs1 + sum8((const float*)&pU1[0][0], j);
                b1 = ro1 * b1 + omr1 * s1;
                float Bth = 0.01f + 1.8f * b1;
                float nm = mem1 * alpha + oma * h1 - Bth * s1;
                mem1 = (mk1 == 0.0f) ? mem1 : nm;
                s1 = (mem1 - Bth > 0.0f) ? mk1 : 0.0f;
                ball = __ballot(s1 != 0.0f);
            }
            if (lane == 0) ballS[w8] = ball;
        } else {
            ull ball = 0;
            int t2 = t - 1;
            if (t2 >= 0 && t2 < TSTEPS) {
                float mk2 = mbit(mb2, t2, j);
                float h2 = bs2 + sum8((const float*)&pU2[0][0], j);
                b2 = ro2 * b2 + omr2 * s2;
                float Bth = 0.01f + 1.8f * b2;
                float nm = mem2 * alpha + oma * h2 - Bth * s2;
                mem2 = (mk2 == 0.0f) ? mem2 : nm;
                s2 = (mem2 - Bth > 0.0f) ? mk2 : 0.0f;
                ball = __ballot(s2 != 0.0f);
            }
            if (lane == 0) ballS[8 + w8] = ball;
            int t3 = t - 2;
            if (t3 >= 0 && t3 < TSTEPS) {
                float mk3 = mbit(mb3, t3, j);
                float h3 = bs3 + sum8((const float*)&pU3[0][0], j);
                b3 = ro3 * b3 + omr3 * s3;
                float Bth = 0.01f + 1.8f * b3;
                float nm = mem3 * alpha + oma * h3 - Bth * s3;
                mem3 = (mk3 == 0.0f) ? mem3 : nm;
                s3 = (mem3 - Bth > 0.0f) ? mk3 : 0.0f;
                cnt3 += s3;                        // deferred output GEMV
            }
        }
        __syncthreads();                           // B2 (cheap)

        // ---------------- build lists from ballots ----------------
        {
            ull bw[16];
            int c[16];
#pragma unroll
            for (int w = 0; w < 16; ++w) { bw[w] = ballS[w]; c[w] = __popcll(bw[w]); }
            int t1 = 0, t2s = 0;
#pragma unroll
            for (int w = 0; w < 8; ++w) { t1 += c[w]; t2s += c[8 + w]; }
            if (lowh) {
                int pos = 0;
#pragma unroll
                for (int w = 0; w < 8; ++w) if (w < w8) pos += c[w];
                pos += __popcll(bw[w8] & ((1ull << lane) - 1ull));
                if ((bw[w8] >> lane) & 1ull) L1[pos] = (unsigned)j << 11;
            } else {
                int pos = 0;
#pragma unroll
                for (int w = 0; w < 8; ++w) if (w < w8) pos += c[8 + w];
                pos += __popcll(bw[8 + w8] & ((1ull << lane) - 1ull));
                if ((bw[8 + w8] >> lane) & 1ull) L2[pos] = (unsigned)j << 11;
            }
            na1 = t1; na2 = t2s;
        }
        __syncthreads();                           // B3 (cheap)
    }

    // ---- output: out[n,o] = (Wo[o,:]·cnt3 + T*bo[o]) / T ----
    float* c3 = (float*)&pU1[0][0];
    if (!lowh) c3[j] = cnt3;
    __syncthreads();
    int wv = tid >> 6;   // 0..15
    for (int o = wv; o < 10; o += 16) {
        float p = 0.0f;
        for (int i = lane; i < H; i += 64)
            p += Wo[o * H + i] * c3[i];
        for (int off = 32; off > 0; off >>= 1)
            p += __shfl_down(p, off);
        if (lane == 0)
            out[n * 10 + o] = (p + 196.0f * bo[o]) / 196.0f;
    }
}

extern "C" void kernel_launch(void* const* d_in, const int* in_sizes, int n_in,
                              void* d_out, int out_size, void* d_ws, size_t ws_size,
                              hipStream_t stream)
{
    const float* x    = (const float*)d_in[0];
    const float* Wi1  = (const float*)d_in[1];
    const float* bi1  = (const float*)d_in[2];
    const float* Wh1  = (const float*)d_in[3];
    const float* bh1  = (const float*)d_in[4];
    const float* Wi2  = (const float*)d_in[5];
    const float* bi2  = (const float*)d_in[6];
    const float* Wh2  = (const float*)d_in[7];
    const float* bh2  = (const float*)d_in[8];
    const float* Wi3  = (const float*)d_in[9];
    const float* bi3  = (const float*)d_in[10];
    const float* Wo   = (const float*)d_in[11];
    const float* bo   = (const float*)d_in[12];
    const float* tau1 = (const float*)d_in[13];
    const float* tau2 = (const float*)d_in[14];
    const float* tau3 = (const float*)d_in[15];
    const float* m1   = (const float*)d_in[16];
    const float* m2   = (const float*)d_in[17];
    const float* m3   = (const float*)d_in[18];

    float* ws  = (float*)d_ws;
    float* out = (float*)d_out;

    // pre-pass: transpose Wh1,Wi2,Wh2,Wi3 into 1MB slots; pack masks to bits
    transpose4<<<dim3(16, 16, 4), dim3(32, 8, 1), 0, stream>>>(Wh1, Wi2, Wh2, Wi3, ws);
    maskbits<<<dim3(TSTEPS, 3, 1), 64, 0, stream>>>(m1, m2, m3, (ull*)(ws + MBOFF_F));

    // main persistent kernel: 1 sample per workgroup (256 WGs, 1024 thr, 16 waves)
    lsnn_main<<<NBATCH, 1024, 0, stream>>>(x, Wi1, bi1, bh1, bi2, bh2, bi3,
                                           Wo, bo, tau1, tau2, tau3, ws, out);
}